// Round 2
// baseline (264.580 us; speedup 1.0000x reference)
//
#include <hip/hip_runtime.h>
#include <hip/hip_fp16.h>
#include <math.h>

#define KOLD 128
#define KNEW 100

// Precompute per-new-edge fractional position within its old bin, and a
// per-old-bin count of how many new edges land in it (packed 4x u8 / dword).
// Row-independent -> tiny 1-block kernel each call (deterministic).
__global__ void edge_map_k(const float* __restrict__ oe,   // 129 old edges
                           const float* __restrict__ ne,   // 101 new edges
                           float* __restrict__ et,         // 101 fractional t
                           unsigned int* __restrict__ cnt) // 32 dwords = 128 u8
{
    __shared__ int ibin[KNEW + 1];
    const int t = threadIdx.x;
    if (t <= KNEW) {
        float e = ne[t];
        int i = 0;
        for (int m = 1; m < KOLD; ++m)
            if (oe[m] <= e) i = m;
        float a = oe[i], b = oe[i + 1];
        float tt = (e - a) / (b - a);
        ibin[t] = i;
        et[t] = fminf(fmaxf(tt, 0.f), 1.f);
    }
    __syncthreads();
    if (t < KOLD / 4) {
        unsigned int w = 0;
        for (int b = 0; b < 4; ++b) {
            int i = t * 4 + b;
            unsigned int c = 0;
            for (int k = 0; k <= KNEW; ++k) c += (ibin[k] == i) ? 1u : 0u;
            w |= (c & 0xffu) << (8 * b);
        }
        cnt[t] = w;
    }
}

// One THREAD per row. Row in VGPRs (static indices only), register tree
// reductions, fused CDF merge-walk (wave-uniform edge counts -> uniform
// branches, zero cross-lane ops). Outputs staged in LDS as f16, flushed
// as coalesced float4 stores.
__launch_bounds__(256, 2)
__global__ void rebin_k(const float* __restrict__ logits,
                        const float* __restrict__ et_g,
                        const unsigned int* __restrict__ cnt_g,
                        float* __restrict__ out, int nrows)
{
    __shared__ float et_s[KNEW + 1];
    __shared__ unsigned int cnt_s[KOLD / 4];
    __shared__ unsigned short obuf[4][64][102];   // pad 102 -> 51-dword stride (odd, conflict-free)

    const int tid  = threadIdx.x;
    const int lane = tid & 63;
    const int wid  = tid >> 6;

    if (tid <= KNEW)     et_s[tid]  = et_g[tid];
    if (tid < KOLD / 4)  cnt_s[tid] = cnt_g[tid];
    __syncthreads();

    const long long row = (long long)blockIdx.x * 256 + tid;
    const int rc = (row < nrows) ? (int)row : (nrows - 1);  // clamp; masked at store

    // ---- load full row into registers (static unroll -> stays in VGPRs)
    float x[KOLD];
    {
        const float4* src = (const float4*)(logits + (size_t)rc * KOLD);
#pragma unroll
        for (int q = 0; q < KOLD / 4; ++q) {
            float4 v = src[q];
            x[4 * q + 0] = v.x; x[4 * q + 1] = v.y;
            x[4 * q + 2] = v.z; x[4 * q + 3] = v.w;
        }
    }

    // ---- max (register tree, no cross-lane)
    float t64[64];
#pragma unroll
    for (int i = 0; i < 64; ++i) t64[i] = fmaxf(x[i], x[i + 64]);
#pragma unroll
    for (int s = 32; s >= 1; s >>= 1) {
#pragma unroll
        for (int i = 0; i < s; ++i) t64[i] = fmaxf(t64[i], t64[i + s]);
    }
    const float m = t64[0];

    // ---- exp in place, then sum (register tree)
#pragma unroll
    for (int i = 0; i < KOLD; ++i) x[i] = __expf(x[i] - m);
#pragma unroll
    for (int i = 0; i < 64; ++i) t64[i] = x[i] + x[i + 64];
#pragma unroll
    for (int s = 32; s >= 1; s >>= 1) {
#pragma unroll
        for (int i = 0; i < s; ++i) t64[i] += t64[i + s];
    }
    const float S    = t64[0];
    const float invS = 1.0f / S;
    const float tiny = 1.1754943508222875e-38f;

    // ---- fused CDF merge-walk over old bins; uniform inner trip counts
    float cum = 0.f, Fp = 0.f;
    int k = 0;
    unsigned short* orow = &obuf[wid][lane][0];
#pragma unroll
    for (int i = 0; i < KOLD; ++i) {
        const float e = x[i];
        int c = (int)((cnt_s[i >> 2] >> ((i & 3) * 8)) & 0xffu);
        while (c-- > 0) {
            float F = fmaf(e, et_s[k], cum);   // unnormalized CDF at edge k
            if (k > 0) {
                float dv = fmaxf(F - Fp, 0.f) * invS + tiny;
                __half h = __float2half(__logf(dv));
                orow[k - 1] = __half_as_ushort(h);
            }
            Fp = F;
            ++k;
        }
        cum += e;
    }

    __syncthreads();

    // ---- coalesced flush: each wave writes its own 64 rows (64*100 = 6400 f32)
    const long long wrow0 = (long long)blockIdx.x * 256 + (long long)wid * 64;
    float* gbase = out + wrow0 * KNEW;
    const long long lim = (long long)nrows * KNEW - wrow0 * KNEW;
    const unsigned int* pw = (const unsigned int*)&obuf[wid][0][0];
#pragma unroll
    for (int it = 0; it < 25; ++it) {
        const int idx = it * 256 + lane * 4;          // element index in [64][100] row-major
        const int r  = (idx * 5243) >> 19;            // exact /100 for idx < 6400
        const int c0 = idx - r * 100;                 // c0 % 4 == 0
        const unsigned int w0 = pw[51 * r + (c0 >> 1)];
        const unsigned int w1 = pw[51 * r + (c0 >> 1) + 1];
        const float2 f0 = __half22float2(*(const __half2*)&w0);
        const float2 f1 = __half22float2(*(const __half2*)&w1);
        if ((long long)idx < lim) {
            float4 o; o.x = f0.x; o.y = f0.y; o.z = f1.x; o.w = f1.y;
            *(float4*)(gbase + idx) = o;
        }
    }
}

extern "C" void kernel_launch(void* const* d_in, const int* in_sizes, int n_in,
                              void* d_out, int out_size, void* d_ws, size_t ws_size,
                              hipStream_t stream) {
    const float* logits = (const float*)d_in[0];
    const float* oe     = (const float*)d_in[1];
    const float* ne     = (const float*)d_in[2];
    float* out          = (float*)d_out;
    const int nrows     = in_sizes[0] / KOLD;

    float*        et  = (float*)d_ws;                       // 101 floats
    unsigned int* cnt = (unsigned int*)((char*)d_ws + 512); // 32 dwords

    edge_map_k<<<1, 128, 0, stream>>>(oe, ne, et, cnt);

    const int blocks = (nrows + 255) / 256;   // one thread per row
    rebin_k<<<blocks, 256, 0, stream>>>(logits, et, cnt, out, nrows);
}

// Round 3
// 107.300 us; speedup vs baseline: 2.4658x; 2.4658x over previous
//
#include <hip/hip_runtime.h>
#include <math.h>

#define KOLD 128
#define KNEW 100

// Precompute (row-independent, tiny 1-block kernel):
//  et[k]   : fractional position of new edge k within its old bin
//  cnt[b]  : # new edges in old bin b, packed 4x u8 per dword (32 dwords)
//  seg[s]  : first edge index k with old-bin(k) >= 32*s   (s=0..3), seg[4]=101
__global__ void edge_map_k(const float* __restrict__ oe,
                           const float* __restrict__ ne,
                           float* __restrict__ et,
                           unsigned int* __restrict__ cnt,
                           int* __restrict__ seg) {
    __shared__ int ibin[KNEW + 1];
    const int t = threadIdx.x;
    if (t <= KNEW) {
        float e = ne[t];
        int i = 0;
        for (int m = 1; m < KOLD; ++m)
            if (oe[m] <= e) i = m;
        float a = oe[i], b = oe[i + 1];
        float tt = (e - a) / (b - a);
        ibin[t] = i;
        et[t] = fminf(fmaxf(tt, 0.f), 1.f);
    }
    __syncthreads();
    if (t < KOLD / 4) {
        unsigned int w = 0;
        for (int b = 0; b < 4; ++b) {
            int i = t * 4 + b;
            unsigned int c = 0;
            for (int k = 0; k <= KNEW; ++k) c += (ibin[k] == i) ? 1u : 0u;
            w |= (c & 0xffu) << (8 * b);
        }
        cnt[t] = w;
    }
    if (t < 4) {
        int ks = KNEW + 1;
        for (int k = 0; k <= KNEW; ++k)
            if (ibin[k] >= 32 * t) { ks = k; break; }
        seg[t] = ks;
    }
    if (t == 4) seg[4] = KNEW + 1;
}

// 4 threads per row; each owns 32 logits in VGPRs (no spill).
// Register trees + 4-lane shuffles for max/sum/prefix; per-segment CDF walk;
// one shfl_up patches the cross-segment diff. f32 LDS staging, coalesced flush.
__launch_bounds__(256, 4)
__global__ void rebin_k(const float* __restrict__ logits,
                        const float* __restrict__ et_g,
                        const unsigned int* __restrict__ cnt_g,
                        const int* __restrict__ seg_g,
                        float* __restrict__ out, int nrows)
{
    __shared__ float et_s[KNEW + 1];
    __shared__ unsigned int cnt_s[KOLD / 4];
    __shared__ int seg_s[5];
    __shared__ float obuf[4][16][KNEW + 1];   // [wave][rowInWave][j], stride 101 (odd)

    const int tid  = threadIdx.x;
    const int lane = tid & 63;
    const int wid  = tid >> 6;
    const int g    = lane >> 2;      // row within wave (0..15)
    const int s    = lane & 3;       // segment (0..3) = old bins [32s, 32s+32)

    if (tid <= KNEW)    et_s[tid]  = et_g[tid];
    if (tid < KOLD / 4) cnt_s[tid] = cnt_g[tid];
    if (tid < 5)        seg_s[tid] = seg_g[tid];
    __syncthreads();

    const long long row = (long long)blockIdx.x * 64 + wid * 16 + g;
    const int rc = (row < nrows) ? (int)row : (nrows - 1);   // clamp; stores guarded

    // ---- load 32 contiguous logits (8x float4) into registers
    float x[32];
    {
        const float4* src = (const float4*)(logits + (size_t)rc * KOLD + s * 32);
#pragma unroll
        for (int q = 0; q < 8; ++q) {
            float4 v = src[q];
            x[4 * q + 0] = v.x; x[4 * q + 1] = v.y;
            x[4 * q + 2] = v.z; x[4 * q + 3] = v.w;
        }
    }

    // ---- max: register tree + 2-step width-4 butterfly
    float t16[16];
#pragma unroll
    for (int i = 0; i < 16; ++i) t16[i] = fmaxf(x[i], x[i + 16]);
#pragma unroll
    for (int st = 8; st >= 1; st >>= 1)
#pragma unroll
        for (int i = 0; i < st; ++i) t16[i] = fmaxf(t16[i], t16[i + st]);
    float m = t16[0];
    m = fmaxf(m, __shfl_xor(m, 1, 64));
    m = fmaxf(m, __shfl_xor(m, 2, 64));

    // ---- exp in place + local sum tree
#pragma unroll
    for (int i = 0; i < 32; ++i) x[i] = __expf(x[i] - m);
#pragma unroll
    for (int i = 0; i < 16; ++i) t16[i] = x[i] + x[i + 16];
#pragma unroll
    for (int st = 8; st >= 1; st >>= 1)
#pragma unroll
        for (int i = 0; i < st; ++i) t16[i] += t16[i + st];
    const float sl = t16[0];

    // ---- 4-lane total + exclusive prefix
    const float v1   = __shfl_xor(sl, 1, 64);   // partner's local sum
    const float pair = sl + v1;
    const float v2   = __shfl_xor(pair, 2, 64); // other pair's sum
    const float S    = pair + v2;
    const float B    = ((s & 2) ? v2 : 0.f) + ((s & 1) ? v1 : 0.f); // excl prefix
    const float invS = 1.0f / S;
    const float tiny = 1.1754943508222875e-38f;

    // ---- per-segment counts into regs (static indices)
    unsigned int cw[8];
#pragma unroll
    for (int q = 0; q < 8; ++q) cw[q] = cnt_s[s * 8 + q];

    // ---- CDF walk over this segment's 32 bins / ~25 edges
    const int ks = seg_s[s];
    const int ke = seg_s[s + 1];
    int k = ks;
    float cum = B, Fp = 0.f, Ffirst = 0.f;
    float* orow = &obuf[wid][g][0];
#pragma unroll
    for (int i = 0; i < 32; ++i) {
        const float e = x[i];
        int c = (int)((cw[i >> 2] >> ((i & 3) * 8)) & 0xffu);
        while (c-- > 0) {
            float F = fmaf(e, et_s[k], cum);
            if (k > ks) orow[k - 1] = __logf(fmaxf(F - Fp, 0.f) * invS + tiny);
            else        Ffirst = F;
            Fp = F;
            ++k;
        }
        cum += e;
    }

    // ---- cross-segment boundary diff via one shuffle
    const float prevLast = __shfl_up(Fp, 1, 4);
    if (s > 0 && ks > 0 && ks < ke)
        orow[ks - 1] = __logf(fmaxf(Ffirst - prevLast, 0.f) * invS + tiny);

    __syncthreads();

    // ---- coalesced flush: wave writes its 16 rows (1600 f32)
    const long long wrow0 = (long long)blockIdx.x * 64 + (long long)wid * 16;
    float* gbase = out + wrow0 * KNEW;
    const long long lim = (long long)nrows * KNEW - wrow0 * KNEW;
    const float* pb = &obuf[wid][0][0];
#pragma unroll
    for (int it = 0; it < 25; ++it) {
        const int idx = it * 64 + lane;            // 0..1599 over [16][100] row-major
        const int r = (idx * 5243) >> 19;          // exact /100 for idx < 6400
        const int c = idx - r * 100;
        const float v = pb[101 * r + c];
        if ((long long)idx < lim) gbase[idx] = v;
    }
}

extern "C" void kernel_launch(void* const* d_in, const int* in_sizes, int n_in,
                              void* d_out, int out_size, void* d_ws, size_t ws_size,
                              hipStream_t stream) {
    const float* logits = (const float*)d_in[0];
    const float* oe     = (const float*)d_in[1];
    const float* ne     = (const float*)d_in[2];
    float* out          = (float*)d_out;
    const int nrows     = in_sizes[0] / KOLD;

    float*        et  = (float*)d_ws;                        // 101 floats
    unsigned int* cnt = (unsigned int*)((char*)d_ws + 512);  // 32 dwords
    int*          seg = (int*)((char*)d_ws + 768);           // 5 ints

    edge_map_k<<<1, 128, 0, stream>>>(oe, ne, et, cnt, seg);

    const int blocks = (nrows + 63) / 64;   // 64 rows per 256-thread block
    rebin_k<<<blocks, 256, 0, stream>>>(logits, et, cnt, seg, out, nrows);
}

// Round 4
// 105.127 us; speedup vs baseline: 2.5168x; 1.0207x over previous
//
#include <hip/hip_runtime.h>
#include <hip/hip_fp16.h>
#include <math.h>

#define KOLD 128
#define KNEW 100

// Precompute (row-independent, tiny 1-block kernel):
//  et[k]   : fractional position of new edge k within its old bin
//  cnt[b]  : # new edges in old bin b, packed 4x u8 per dword (32 dwords)
//  seg[s]  : first edge index k with old-bin(k) >= 32*s   (s=0..3), seg[4]=101
__global__ void edge_map_k(const float* __restrict__ oe,
                           const float* __restrict__ ne,
                           float* __restrict__ et,
                           unsigned int* __restrict__ cnt,
                           int* __restrict__ seg) {
    __shared__ int ibin[KNEW + 1];
    const int t = threadIdx.x;
    if (t <= KNEW) {
        float e = ne[t];
        int i = 0;
        for (int m = 1; m < KOLD; ++m)
            if (oe[m] <= e) i = m;
        float a = oe[i], b = oe[i + 1];
        float tt = (e - a) / (b - a);
        ibin[t] = i;
        et[t] = fminf(fmaxf(tt, 0.f), 1.f);
    }
    __syncthreads();
    if (t < KOLD / 4) {
        unsigned int w = 0;
        for (int b = 0; b < 4; ++b) {
            int i = t * 4 + b;
            unsigned int c = 0;
            for (int k = 0; k <= KNEW; ++k) c += (ibin[k] == i) ? 1u : 0u;
            w |= (c & 0xffu) << (8 * b);
        }
        cnt[t] = w;
    }
    if (t < 4) {
        int ks = KNEW + 1;
        for (int k = 0; k <= KNEW; ++k)
            if (ibin[k] >= 32 * t) { ks = k; break; }
        seg[t] = ks;
    }
    if (t == 4) seg[4] = KNEW + 1;
}

// 4 threads per row; each owns 32 logits in VGPRs. 4-accumulator reduction
// trees (low reg pressure), 4-lane shuffles for max/sum/prefix, per-segment
// CDF walk. Outputs staged f16 in LDS (validated R2: absmax unchanged),
// flushed as float4 stores. Per-wave staging -> no block barrier needed.
__launch_bounds__(256, 6)
__global__ void rebin_k(const float* __restrict__ logits,
                        const float* __restrict__ et_g,
                        const unsigned int* __restrict__ cnt_g,
                        const int* __restrict__ seg_g,
                        float* __restrict__ out, int nrows)
{
    __shared__ float et_s[KNEW + 1];
    __shared__ unsigned int cnt_s[KOLD / 4];
    __shared__ int seg_s[5];
    __shared__ unsigned int obuf[4][16][52];   // f16 pairs: [wave][row][52 u32 = 104 halves]

    const int tid  = threadIdx.x;
    const int lane = tid & 63;
    const int wid  = tid >> 6;
    const int g    = lane >> 2;      // row within wave (0..15)
    const int s    = lane & 3;       // segment = old bins [32s, 32s+32)

    if (tid <= KNEW)    et_s[tid]  = et_g[tid];
    if (tid < KOLD / 4) cnt_s[tid] = cnt_g[tid];
    if (tid < 5)        seg_s[tid] = seg_g[tid];
    __syncthreads();

    const long long row = (long long)blockIdx.x * 64 + wid * 16 + g;
    const int rc = (row < nrows) ? (int)row : (nrows - 1);   // clamp; stores guarded

    // ---- load 32 contiguous logits (8x float4) into registers
    float x[32];
    {
        const float4* src = (const float4*)(logits + (size_t)rc * KOLD + s * 32);
#pragma unroll
        for (int q = 0; q < 8; ++q) {
            float4 v = src[q];
            x[4 * q + 0] = v.x; x[4 * q + 1] = v.y;
            x[4 * q + 2] = v.z; x[4 * q + 3] = v.w;
        }
    }

    // ---- max: 4 accumulators + 4-lane butterfly
    float a0 = x[0], a1 = x[1], a2 = x[2], a3 = x[3];
#pragma unroll
    for (int i = 4; i < 32; i += 4) {
        a0 = fmaxf(a0, x[i]);     a1 = fmaxf(a1, x[i + 1]);
        a2 = fmaxf(a2, x[i + 2]); a3 = fmaxf(a3, x[i + 3]);
    }
    float m = fmaxf(fmaxf(a0, a1), fmaxf(a2, a3));
    m = fmaxf(m, __shfl_xor(m, 1, 64));
    m = fmaxf(m, __shfl_xor(m, 2, 64));

    // ---- exp in place + local sum (4 accumulators)
#pragma unroll
    for (int i = 0; i < 32; ++i) x[i] = __expf(x[i] - m);
    a0 = x[0]; a1 = x[1]; a2 = x[2]; a3 = x[3];
#pragma unroll
    for (int i = 4; i < 32; i += 4) {
        a0 += x[i]; a1 += x[i + 1]; a2 += x[i + 2]; a3 += x[i + 3];
    }
    const float sl = (a0 + a1) + (a2 + a3);

    // ---- 4-lane total + exclusive prefix
    const float v1   = __shfl_xor(sl, 1, 64);
    const float pair = sl + v1;
    const float v2   = __shfl_xor(pair, 2, 64);
    const float S    = pair + v2;
    const float B    = ((s & 2) ? v2 : 0.f) + ((s & 1) ? v1 : 0.f);
    const float invS = 1.0f / S;
    const float tiny = 1.1754943508222875e-38f;

    // ---- per-segment counts into regs
    unsigned int cw[8];
#pragma unroll
    for (int q = 0; q < 8; ++q) cw[q] = cnt_s[s * 8 + q];

    // ---- CDF walk over this segment's 32 bins / ~25 edges
    const int ks = seg_s[s];
    const int ke = seg_s[s + 1];
    int k = ks;
    float cum = B, Fp = 0.f, Ffirst = 0.f;
    unsigned short* orow = (unsigned short*)&obuf[wid][g][0];
#pragma unroll
    for (int i = 0; i < 32; ++i) {
        const float e = x[i];
        int c = (int)((cw[i >> 2] >> ((i & 3) * 8)) & 0xffu);
        while (c-- > 0) {
            float F = fmaf(e, et_s[k], cum);
            if (k > ks) {
                float lv = __logf(fmaxf(F - Fp, 0.f) * invS + tiny);
                orow[k - 1] = __half_as_ushort(__float2half(lv));
            } else Ffirst = F;
            Fp = F;
            ++k;
        }
        cum += e;
    }

    // ---- cross-segment boundary diff via one shuffle
    const float prevLast = __shfl_up(Fp, 1, 4);
    if (s > 0 && ks > 0 && ks < ke) {
        float lv = __logf(fmaxf(Ffirst - prevLast, 0.f) * invS + tiny);
        orow[ks - 1] = __half_as_ushort(__float2half(lv));
    }

    // wave-internal: flush reads only this wave's obuf slice -> no block barrier
    asm volatile("s_waitcnt lgkmcnt(0)" ::: "memory");

    // ---- coalesced flush: wave writes its 16 rows as float4 (7 iterations)
    const int wrow0 = blockIdx.x * 64 + wid * 16;
    float* gbase = out + (long long)wrow0 * KNEW;
    const int rem  = nrows - wrow0;                     // rows this wave still owns
    const int lim4 = rem >= 16 ? 400 : (rem > 0 ? rem * 25 : 0);
    const unsigned int* pw = &obuf[wid][0][0];
#pragma unroll
    for (int it = 0; it < 7; ++it) {
        const int idx4  = it * 64 + lane;               // float4 index over [16][25]
        const int idx4c = idx4 < 399 ? idx4 : 399;      // clamp (avoid LDS OOB)
        const int r  = (idx4c * 5243) >> 17;            // exact /25 for idx4c < 400
        const int c4 = idx4c - r * 25;
        const unsigned int w0 = pw[52 * r + 2 * c4];
        const unsigned int w1 = pw[52 * r + 2 * c4 + 1];
        const float2 f0 = __half22float2(*(const __half2*)&w0);
        const float2 f1 = __half22float2(*(const __half2*)&w1);
        if (idx4 < lim4) {
            float4 o; o.x = f0.x; o.y = f0.y; o.z = f1.x; o.w = f1.y;
            *(float4*)(gbase + idx4 * 4) = o;
        }
    }
}

extern "C" void kernel_launch(void* const* d_in, const int* in_sizes, int n_in,
                              void* d_out, int out_size, void* d_ws, size_t ws_size,
                              hipStream_t stream) {
    const float* logits = (const float*)d_in[0];
    const float* oe     = (const float*)d_in[1];
    const float* ne     = (const float*)d_in[2];
    float* out          = (float*)d_out;
    const int nrows     = in_sizes[0] / KOLD;

    float*        et  = (float*)d_ws;                        // 101 floats
    unsigned int* cnt = (unsigned int*)((char*)d_ws + 512);  // 32 dwords
    int*          seg = (int*)((char*)d_ws + 768);           // 5 ints

    edge_map_k<<<1, 128, 0, stream>>>(oe, ne, et, cnt, seg);

    const int blocks = (nrows + 63) / 64;   // 64 rows per 256-thread block
    rebin_k<<<blocks, 256, 0, stream>>>(logits, et, cnt, seg, out, nrows);
}